// Round 6
// baseline (352.065 us; speedup 1.0000x reference)
//
#include <hip/hip_runtime.h>

#define E 300
#define P 5
#define H 200
#define S 256
#define L 34
#define B 8
#define NI 254   // pivot positions i = 1..254

typedef __attribute__((ext_vector_type(8))) short short8;
typedef __attribute__((ext_vector_type(4))) float f32x4;

// ws layout (floats; 16B-aligned offsets)
#define TOKB_OFF   0            // tokb bf16[8][258][300] (+slack)
#define TOKB_FL    309632
#define WR3_OFF    309632       // Wr3[208][928] bf16
#define WR3_FL     96512
#define FCWB_OFF   406144       // fcWb[48][1344] bf16
#define FCWB_FL    32256
#define G_OFF      438400       // g bf16[512][200]
#define G_FL       51200
#define C0_OFF     489600       // c0 bf16[254][200]
#define C0_FL      25400
#define C255_OFF   515000       // c255 bf16[254][200]
#define C255_FL    25400
#define CT_OFF     540400       // ct bf16[b][j][h]
#define CT_FL      204800
#define POOLBF_OFF 745200       // poolbf bf16[b][256][416]
#define POOLBF_FL  425984
// total 1,171,184 floats = 4.7 MB

__device__ __forceinline__ unsigned short f2bf(float f) {
    unsigned u = __float_as_uint(f);
    unsigned r = (u + 0x7FFFu + ((u >> 16) & 1u)) >> 16;   // RNE
    return (unsigned short)r;
}
__device__ __forceinline__ float bfu(unsigned short s) {
    return __uint_as_float(((unsigned)s) << 16);
}
__device__ __forceinline__ float4 bf4(ushort4 u) {
    return make_float4(bfu(u.x), bfu(u.y), bfu(u.z), bfu(u.w));
}
__device__ __forceinline__ short8 load_a8(const unsigned short* p) {
    short8 r;
    ((ushort4*)&r)[0] = *(const ushort4*)p;        // 8B-aligned
    ((ushort4*)&r)[1] = *(const ushort4*)(p + 4);
    return r;
}
__device__ __forceinline__ float4 add4(float4 a, float4 b) {
    return make_float4(a.x+b.x, a.y+b.y, a.z+b.z, a.w+b.w);
}
__device__ __forceinline__ float4 max4(float4 a, float4 b) {
    return make_float4(fmaxf(a.x,b.x), fmaxf(a.y,b.y), fmaxf(a.z,b.z), fmaxf(a.w,b.w));
}

#define GA_BLOCKS 605    // gather part: 154800 float4-groups
#define PREP_BLOCKS 1803 // prep part: 461536 items

// ---------------- A: fused init = embedding gather + weight repacks + pf tables ----
__global__ __launch_bounds__(256) void k_init(const int* __restrict__ ids,
                                              const float* __restrict__ we,
                                              const float* __restrict__ convW,
                                              const float* __restrict__ fcW,
                                              const float* __restrict__ pf,
                                              unsigned short* __restrict__ tokb,
                                              unsigned short* __restrict__ Wr3,
                                              unsigned short* __restrict__ fcWb,
                                              unsigned short* __restrict__ g,
                                              unsigned short* __restrict__ c0,
                                              unsigned short* __restrict__ c255) {
    if (blockIdx.x < GA_BLOCKS) {
        // tokb bf16[b][258][300], rows 0 & 257 zero
        int idx = blockIdx.x * 256 + threadIdx.x;
        const int total = B * 258 * 75;
        if (idx >= total) return;
        int row = idx / 75;
        int col = idx - row * 75;
        int b = row / 258;
        int r = row - b * 258;
        float4 v = make_float4(0.f, 0.f, 0.f, 0.f);
        if (r >= 1 && r <= 256) {
            int id = ids[b * S + (r - 1)];
            v = ((const float4*)we)[(size_t)id * 75 + col];
        }
        ushort4 o;
        o.x = f2bf(v.x); o.y = f2bf(v.y); o.z = f2bf(v.z); o.w = f2bf(v.w);
        *(ushort4*)(tokb + (size_t)row * 300 + col * 4) = o;
        return;
    }
    int idx = (blockIdx.x - GA_BLOCKS) * 256 + threadIdx.x;
    if (idx < 193024) {                            // Wr3: 208x928, Wr3[h][r*300+e]
        int hh = idx / 928, kk = idx - hh * 928;
        float v = 0.f;
        if (hh < H && kk < 900) {
            int r = kk / 300, e = kk - r * 300;
            v = convW[hh * 915 + e * 3 + r];
        }
        Wr3[idx] = f2bf(v);
    } else if (idx < 257536) {                     // fcWb: 48x1344
        int t = idx - 193024;
        int l = t / 1344, c = t - l * 1344;
        float v = 0.f;
        if (l < L) {
            if (c < 400) v = fcW[l * 1300 + c];
            else if (c >= 416 && c < 1316) v = fcW[l * 1300 + 400 + (c - 416)];
        }
        fcWb[t] = f2bf(v);
    } else if (idx < 359936) {                     // g[t2][h], t2 = (j-i)+256
        int t = idx - 257536;
        int t2 = t / H, h = t - t2 * H;
        int d = t2 - 256;
        float a = 0.f;
#pragma unroll
        for (int k = 0; k < 3; k++) {
            int r = d + k - 1; r = (r < 0) ? -r : r; if (r > 255) r = 255;
#pragma unroll
            for (int q = 0; q < P; q++)
                a += convW[h * 915 + (E + q) * 3 + k] * pf[r * P + q];
        }
        g[t] = f2bf(a);
    } else if (idx < 410736) {                     // c0: j=0, tap k=0 dropped
        int t = idx - 359936;
        int m = t / H, h = t - m * H;
        int i = m + 1;
        float a = 0.f;
#pragma unroll
        for (int q = 0; q < P; q++) {
            a += convW[h * 915 + (E + q) * 3 + 1] * pf[i * P + q];
            a += convW[h * 915 + (E + q) * 3 + 2] * pf[(i - 1) * P + q];
        }
        c0[m * H + h] = f2bf(a);
    } else if (idx < 461536) {                     // c255: j=255, tap k=2 dropped
        int t = idx - 410736;
        int m = t / H, h = t - m * H;
        int i = m + 1;
        float a = 0.f;
#pragma unroll
        for (int q = 0; q < P; q++) {
            a += convW[h * 915 + (E + q) * 3 + 0] * pf[(254 - i) * P + q];
            a += convW[h * 915 + (E + q) * 3 + 1] * pf[(255 - i) * P + q];
        }
        c255[m * H + h] = f2bf(a);
    }
}

// ---------------- B: conv_tok GEMM via bf16 MFMA -> ct bf16[b][j][h] ----------------
// M=2048 (b,j), N=208 (h pad), K=928 (pad; zero B cols nullify A overreads).
__global__ __launch_bounds__(256) void k_conv(const unsigned short* __restrict__ tokb,
                                              const unsigned short* __restrict__ Wr3,
                                              const float* __restrict__ convB,
                                              unsigned short* __restrict__ ct) {
    int n0 = blockIdx.x * 16;
    int mg = blockIdx.y;
    int wave = threadIdx.x >> 6;
    int lane = threadIdx.x & 63;
    int quad = lane >> 4;
    int lr = lane & 15;
    int mtile = mg * 4 + wave;
    int b = mtile >> 4;
    int j0 = (mtile & 15) << 4;

    const unsigned short* pa = tokb + ((size_t)(b * 258 + j0 + lr) * 300 + quad * 8);
    const unsigned short* pb = Wr3 + ((size_t)(n0 + lr) * 928 + quad * 8);

    f32x4 acc0 = {0.f, 0.f, 0.f, 0.f};
    f32x4 acc1 = {0.f, 0.f, 0.f, 0.f};
#pragma unroll
    for (int kk = 0; kk + 1 < 29; kk += 2) {
        short8 a0 = load_a8(pa + kk * 32);
        short8 b0 = *(const short8*)(pb + kk * 32);
        acc0 = __builtin_amdgcn_mfma_f32_16x16x32_bf16(a0, b0, acc0, 0, 0, 0);
        short8 a1 = load_a8(pa + kk * 32 + 32);
        short8 b1 = *(const short8*)(pb + kk * 32 + 32);
        acc1 = __builtin_amdgcn_mfma_f32_16x16x32_bf16(a1, b1, acc1, 0, 0, 0);
    }
    {   // tail kk=28
        short8 a0 = load_a8(pa + 28 * 32);
        short8 b0 = *(const short8*)(pb + 28 * 32);
        acc0 = __builtin_amdgcn_mfma_f32_16x16x32_bf16(a0, b0, acc0, 0, 0, 0);
    }
    int h = n0 + lr;
    if (h < H) {
        float bias = convB[h];
#pragma unroll
        for (int r = 0; r < 4; r++)
            ct[(size_t)(b * 256 + j0 + quad * 4 + r) * 200 + h] = f2bf(acc0[r] + acc1[r] + bias);
    }
}

// ---------------- C: dynamic max pool (bf16 in) -> poolbf bf16[b][256][416] --------
// grid (64 pg, 8 b); 512 thr = 8 j-subs x 64 lanes (50 active, h=4*lane), 32 j each.
// bf16 b64 loads (half traffic), branch-free 3-range j loop, unroll 8.
__global__ __launch_bounds__(512, 4) void k_poolA(const unsigned short* __restrict__ ct,
                                                  const unsigned short* __restrict__ g,
                                                  const unsigned short* __restrict__ c0,
                                                  const unsigned short* __restrict__ c255,
                                                  unsigned short* __restrict__ poolbf) {
    __shared__ float4 lds4[8 * 4 * 2 * 50];        // [sub][k][lr][lane] 51.2 KB
    int pg = blockIdx.x;
    int b  = blockIdx.y;
    int tid = threadIdx.x;
    int sub = tid >> 6;
    int lane = tid & 63;
    int p0 = pg * 4 + 1;                           // pivots p0..p0+3

    if (lane < 50) {
        int h = lane << 2;
        const unsigned short* ctb = ct + (size_t)b * S * H + h;
        const unsigned short* gb  = g + h;

        float4 aL0 = {0,0,0,0}, aL1 = aL0, aL2 = aL0, aL3 = aL0;
        float4 aR0 = aL0, aR1 = aL0, aR2 = aL0, aR3 = aL0;

        if (sub == 0) {                            // j = 0 special (always left)
            float4 c = bf4(*(const ushort4*)(ctb));
            int m = pg * 4;
            if (m + 0 < NI) aL0 = max4(aL0, add4(c, bf4(*(const ushort4*)(c0 + (m+0) * H + h))));
            if (m + 1 < NI) aL1 = max4(aL1, add4(c, bf4(*(const ushort4*)(c0 + (m+1) * H + h))));
            if (m + 2 < NI) aL2 = max4(aL2, add4(c, bf4(*(const ushort4*)(c0 + (m+2) * H + h))));
            if (m + 3 < NI) aL3 = max4(aL3, add4(c, bf4(*(const ushort4*)(c0 + (m+3) * H + h))));
        }
        if (sub == 7) {                            // j = 255 special (always right)
            float4 c = bf4(*(const ushort4*)(ctb + (size_t)255 * H));
            int m = pg * 4;
            if (m + 0 < NI) aR0 = max4(aR0, add4(c, bf4(*(const ushort4*)(c255 + (m+0) * H + h))));
            if (m + 1 < NI) aR1 = max4(aR1, add4(c, bf4(*(const ushort4*)(c255 + (m+1) * H + h))));
            if (m + 2 < NI) aR2 = max4(aR2, add4(c, bf4(*(const ushort4*)(c255 + (m+2) * H + h))));
            if (m + 3 < NI) aR3 = max4(aR3, add4(c, bf4(*(const ushort4*)(c255 + (m+3) * H + h))));
        }

        int js = (sub == 0) ? 1 : sub * 32;
        int je = (sub == 7) ? 254 : sub * 32 + 31;

        // rolling g rows (f32 after cvt): grk holds g[(j - p0 - k + 256)*H + h]
        float4 gr0 = bf4(*(const ushort4*)(gb + (size_t)(js - p0 + 256) * H));
        float4 gr1 = bf4(*(const ushort4*)(gb + (size_t)(js - p0 + 255) * H));
        float4 gr2 = bf4(*(const ushort4*)(gb + (size_t)(js - p0 + 254) * H));
        float4 gr3 = bf4(*(const ushort4*)(gb + (size_t)(js - p0 + 253) * H));

        int eL = (je + 1 < p0) ? (je + 1) : p0;        // [js, eL): all-left
        int mS = (js > p0) ? js : p0;                  // [mS, eM): mixed (<=4)
        int eM = (je + 1 < p0 + 4) ? (je + 1) : (p0 + 4);
        int rS = (js > p0 + 4) ? js : (p0 + 4);        // [rS, je]: all-right

#pragma unroll 8
        for (int j = js; j < eL; ++j) {
            float4 c = bf4(*(const ushort4*)(ctb + (size_t)j * H));
            aL0 = max4(aL0, add4(c, gr0));
            aL1 = max4(aL1, add4(c, gr1));
            aL2 = max4(aL2, add4(c, gr2));
            aL3 = max4(aL3, add4(c, gr3));
            gr3 = gr2; gr2 = gr1; gr1 = gr0;
            gr0 = bf4(*(const ushort4*)(gb + (size_t)(j + 1 - p0 + 256) * H));
        }
        for (int j = mS; j < eM; ++j) {                // <= 4 iterations
            float4 c = bf4(*(const ushort4*)(ctb + (size_t)j * H));
            float4 v0 = add4(c, gr0);
            float4 v1 = add4(c, gr1);
            float4 v2 = add4(c, gr2);
            float4 v3 = add4(c, gr3);
            if (j < p0)     aL0 = max4(aL0, v0); else aR0 = max4(aR0, v0);
            if (j < p0 + 1) aL1 = max4(aL1, v1); else aR1 = max4(aR1, v1);
            if (j < p0 + 2) aL2 = max4(aL2, v2); else aR2 = max4(aR2, v2);
            if (j < p0 + 3) aL3 = max4(aL3, v3); else aR3 = max4(aR3, v3);
            gr3 = gr2; gr2 = gr1; gr1 = gr0;
            gr0 = bf4(*(const ushort4*)(gb + (size_t)(j + 1 - p0 + 256) * H));
        }
#pragma unroll 8
        for (int j = rS; j <= je; ++j) {
            float4 c = bf4(*(const ushort4*)(ctb + (size_t)j * H));
            aR0 = max4(aR0, add4(c, gr0));
            aR1 = max4(aR1, add4(c, gr1));
            aR2 = max4(aR2, add4(c, gr2));
            aR3 = max4(aR3, add4(c, gr3));
            gr3 = gr2; gr2 = gr1; gr1 = gr0;
            gr0 = bf4(*(const ushort4*)(gb + (size_t)(j + 1 - p0 + 256) * H));
        }

        float4* lp = lds4 + (size_t)sub * 400 + lane;
        lp[0]   = aL0; lp[50]  = aR0;
        lp[100] = aL1; lp[150] = aR1;
        lp[200] = aL2; lp[250] = aR2;
        lp[300] = aL3; lp[350] = aR3;
    }
    __syncthreads();

    if (tid < 400) {
        int k = tid / 100;
        int r = tid - k * 100;
        int half = r / 50;
        int ln = r - half * 50;
        int slot = (k * 2 + half) * 50 + ln;
        float4 v = lds4[slot];
#pragma unroll
        for (int s2 = 1; s2 < 8; s2++) v = max4(v, lds4[s2 * 400 + slot]);
        int m = pg * 4 + k;
        if (m < NI) {
            ushort4 o;
            o.x = f2bf(v.x); o.y = f2bf(v.y); o.z = f2bf(v.z); o.w = f2bf(v.w);
            *(ushort4*)(poolbf + (size_t)(b * 256 + m + 1) * 416 + half * 200 + ln * 4) = o;
        }
    } else if (tid < 464) {                        // zero K-pad cols 400..415
        int t = tid - 400;
        int k = t >> 4, c = t & 15;
        int m = pg * 4 + k;
        if (m < NI) poolbf[(size_t)(b * 256 + m + 1) * 416 + 400 + c] = 0;
    }
}

// ---------------- D: fused FC GEMM (both K-parts) + bias + end padding -> out ------
// M=2048 (b,s), N=48 (l pad). K part0 = pool (416), part1 = llf via tokb (928).
// Rows s=0,255 are garbage in A; overridden by the pad in the epilogue.
__global__ __launch_bounds__(256) void k_fc(const unsigned short* __restrict__ poolbf,
                                            const unsigned short* __restrict__ tokb,
                                            const unsigned short* __restrict__ fcWb,
                                            const float* __restrict__ fcB,
                                            float* __restrict__ out) {
    int n0 = blockIdx.x * 16;
    int mg = blockIdx.y;
    int wave = threadIdx.x >> 6;
    int lane = threadIdx.x & 63;
    int quad = lane >> 4;
    int lr = lane & 15;
    int mtile = mg * 4 + wave;
    int b = mtile >> 4;
    int s0 = (mtile & 15) << 4;

    const unsigned short* pa0 = poolbf + ((size_t)(b * 256 + s0 + lr) * 416 + quad * 8);
    const unsigned short* pa1 = tokb + ((size_t)(b * 258 + s0 + lr) * 300 + quad * 8);
    const unsigned short* pb0 = fcWb + ((size_t)(n0 + lr) * 1344 + quad * 8);
    const unsigned short* pb1 = pb0 + 416;

    f32x4 acc0 = {0.f, 0.f, 0.f, 0.f};
    f32x4 acc1 = {0.f, 0.f, 0.f, 0.f};
    int kk = 0;
#pragma unroll 3
    for (kk = 0; kk + 1 < 13; kk += 2) {
        short8 a0 = load_a8(pa0 + kk * 32);
        short8 b0 = *(const short8*)(pb0 + kk * 32);
        acc0 = __builtin_amdgcn_mfma_f32_16x16x32_bf16(a0, b0, acc0, 0, 0, 0);
        short8 a1 = load_a8(pa0 + kk * 32 + 32);
        short8 b1 = *(const short8*)(pb0 + kk * 32 + 32);
        acc1 = __builtin_amdgcn_mfma_f32_16x16x32_bf16(a1, b1, acc1, 0, 0, 0);
    }
    {   // part0 tail kk=12
        short8 a0 = load_a8(pa0 + 12 * 32);
        short8 b0 = *(const short8*)(pb0 + 12 * 32);
        acc0 = __builtin_amdgcn_mfma_f32_16x16x32_bf16(a0, b0, acc0, 0, 0, 0);
    }
#pragma unroll 4
    for (kk = 0; kk + 1 < 29; kk += 2) {
        short8 a0 = load_a8(pa1 + kk * 32);
        short8 b0 = *(const short8*)(pb1 + kk * 32);
        acc0 = __builtin_amdgcn_mfma_f32_16x16x32_bf16(a0, b0, acc0, 0, 0, 0);
        short8 a1 = load_a8(pa1 + kk * 32 + 32);
        short8 b1 = *(const short8*)(pb1 + kk * 32 + 32);
        acc1 = __builtin_amdgcn_mfma_f32_16x16x32_bf16(a1, b1, acc1, 0, 0, 0);
    }
    {   // part1 tail kk=28
        short8 a0 = load_a8(pa1 + 28 * 32);
        short8 b0 = *(const short8*)(pb1 + 28 * 32);
        acc0 = __builtin_amdgcn_mfma_f32_16x16x32_bf16(a0, b0, acc0, 0, 0, 0);
    }

    int l = n0 + lr;
    if (l < L) {
        float bias = fcB[l];
#pragma unroll
        for (int r = 0; r < 4; r++) {
            int s = s0 + quad * 4 + r;
            float val;
            if (s == 0 || s == S - 1) val = (l == L - 1) ? 1.0f : 0.0f;
            else                      val = acc0[r] + acc1[r] + bias;
            out[(size_t)(b * 256 + s) * L + l] = val;
        }
    }
}

extern "C" void kernel_launch(void* const* d_in, const int* in_sizes, int n_in,
                              void* d_out, int out_size, void* d_ws, size_t ws_size,
                              hipStream_t stream) {
    const int*   ids      = (const int*)d_in[0];
    const float* word_emb = (const float*)d_in[1];
    const float* pf_emb   = (const float*)d_in[2];
    const float* conv_W   = (const float*)d_in[3];
    const float* conv_b   = (const float*)d_in[4];
    const float* fc_W     = (const float*)d_in[5];
    const float* fc_b     = (const float*)d_in[6];
    float* out = (float*)d_out;
    float* ws  = (float*)d_ws;

    unsigned short* tokb   = (unsigned short*)(ws + TOKB_OFF);
    unsigned short* Wr3    = (unsigned short*)(ws + WR3_OFF);
    unsigned short* fcWb   = (unsigned short*)(ws + FCWB_OFF);
    unsigned short* g      = (unsigned short*)(ws + G_OFF);
    unsigned short* c0     = (unsigned short*)(ws + C0_OFF);
    unsigned short* c255   = (unsigned short*)(ws + C255_OFF);
    unsigned short* ct     = (unsigned short*)(ws + CT_OFF);
    unsigned short* poolbf = (unsigned short*)(ws + POOLBF_OFF);

    k_init<<<GA_BLOCKS + PREP_BLOCKS, 256, 0, stream>>>(ids, word_emb, conv_W, fc_W,
                                                        pf_emb, tokb, Wr3, fcWb,
                                                        g, c0, c255);
    k_conv<<<dim3(13, 32), 256, 0, stream>>>(tokb, Wr3, conv_b, ct);
    k_poolA<<<dim3(64, 8), 512, 0, stream>>>(ct, g, c0, c255, poolbf);
    k_fc<<<dim3(3, 32), 256, 0, stream>>>(poolbf, tokb, fcWb, fc_b, out);
}

// Round 7
// 136.462 us; speedup vs baseline: 2.5800x; 2.5800x over previous
//
#include <hip/hip_runtime.h>

#define E 300
#define P 5
#define H 200
#define S 256
#define L 34
#define B 8
#define NI 254   // pivot positions i = 1..254

typedef __attribute__((ext_vector_type(8))) short short8;
typedef __attribute__((ext_vector_type(4))) float f32x4;

// ws layout (floats; 16B-aligned offsets)
#define TOKB_OFF   0            // tokb bf16[8][258][300] (+slack)
#define TOKB_FL    309632
#define WR3_OFF    309632       // Wr3[208][928] bf16
#define WR3_FL     96512
#define FCWB_OFF   406144       // fcWb[48][1344] bf16
#define FCWB_FL    32256
#define G_OFF      438400       // g bf16[512][200]
#define G_FL       51200
#define C0_OFF     489600       // c0 bf16[254][200]
#define C0_FL      25400
#define C255_OFF   515000       // c255 bf16[254][200]
#define C255_FL    25400
#define CT_OFF     540400       // ct bf16[b][j][h]
#define CT_FL      204800
#define POOLBF_OFF 745200       // poolbf bf16[b][256][416]
#define POOLBF_FL  425984
// total 1,171,184 floats = 4.7 MB

__device__ __forceinline__ unsigned short f2bf(float f) {
    unsigned u = __float_as_uint(f);
    unsigned r = (u + 0x7FFFu + ((u >> 16) & 1u)) >> 16;   // RNE
    return (unsigned short)r;
}
__device__ __forceinline__ float bfu(unsigned short s) {
    return __uint_as_float(((unsigned)s) << 16);
}
__device__ __forceinline__ float4 bf4(ushort4 u) {
    return make_float4(bfu(u.x), bfu(u.y), bfu(u.z), bfu(u.w));
}
__device__ __forceinline__ short8 load_a8(const unsigned short* p) {
    short8 r;
    ((ushort4*)&r)[0] = *(const ushort4*)p;        // 8B-aligned
    ((ushort4*)&r)[1] = *(const ushort4*)(p + 4);
    return r;
}
__device__ __forceinline__ float4 add4(float4 a, float4 b) {
    return make_float4(a.x+b.x, a.y+b.y, a.z+b.z, a.w+b.w);
}
__device__ __forceinline__ float4 max4(float4 a, float4 b) {
    return make_float4(fmaxf(a.x,b.x), fmaxf(a.y,b.y), fmaxf(a.z,b.z), fmaxf(a.w,b.w));
}

#define GA_BLOCKS 605    // gather part: 154800 float4-groups
#define PREP_BLOCKS 1803 // prep part: 461536 items

// ---------------- A: fused init = embedding gather + weight repacks + pf tables ----
__global__ __launch_bounds__(256) void k_init(const int* __restrict__ ids,
                                              const float* __restrict__ we,
                                              const float* __restrict__ convW,
                                              const float* __restrict__ fcW,
                                              const float* __restrict__ pf,
                                              unsigned short* __restrict__ tokb,
                                              unsigned short* __restrict__ Wr3,
                                              unsigned short* __restrict__ fcWb,
                                              unsigned short* __restrict__ g,
                                              unsigned short* __restrict__ c0,
                                              unsigned short* __restrict__ c255) {
    if (blockIdx.x < GA_BLOCKS) {
        // tokb bf16[b][258][300], rows 0 & 257 zero
        int idx = blockIdx.x * 256 + threadIdx.x;
        const int total = B * 258 * 75;
        if (idx >= total) return;
        int row = idx / 75;
        int col = idx - row * 75;
        int b = row / 258;
        int r = row - b * 258;
        float4 v = make_float4(0.f, 0.f, 0.f, 0.f);
        if (r >= 1 && r <= 256) {
            int id = ids[b * S + (r - 1)];
            v = ((const float4*)we)[(size_t)id * 75 + col];
        }
        ushort4 o;
        o.x = f2bf(v.x); o.y = f2bf(v.y); o.z = f2bf(v.z); o.w = f2bf(v.w);
        *(ushort4*)(tokb + (size_t)row * 300 + col * 4) = o;
        return;
    }
    int idx = (blockIdx.x - GA_BLOCKS) * 256 + threadIdx.x;
    if (idx < 193024) {                            // Wr3: 208x928, Wr3[h][r*300+e]
        int hh = idx / 928, kk = idx - hh * 928;
        float v = 0.f;
        if (hh < H && kk < 900) {
            int r = kk / 300, e = kk - r * 300;
            v = convW[hh * 915 + e * 3 + r];
        }
        Wr3[idx] = f2bf(v);
    } else if (idx < 257536) {                     // fcWb: 48x1344
        int t = idx - 193024;
        int l = t / 1344, c = t - l * 1344;
        float v = 0.f;
        if (l < L) {
            if (c < 400) v = fcW[l * 1300 + c];
            else if (c >= 416 && c < 1316) v = fcW[l * 1300 + 400 + (c - 416)];
        }
        fcWb[t] = f2bf(v);
    } else if (idx < 359936) {                     // g[t2][h], t2 = (j-i)+256
        int t = idx - 257536;
        int t2 = t / H, h = t - t2 * H;
        int d = t2 - 256;
        float a = 0.f;
#pragma unroll
        for (int k = 0; k < 3; k++) {
            int r = d + k - 1; r = (r < 0) ? -r : r; if (r > 255) r = 255;
#pragma unroll
            for (int q = 0; q < P; q++)
                a += convW[h * 915 + (E + q) * 3 + k] * pf[r * P + q];
        }
        g[t] = f2bf(a);
    } else if (idx < 410736) {                     // c0: j=0, tap k=0 dropped
        int t = idx - 359936;
        int m = t / H, h = t - m * H;
        int i = m + 1;
        float a = 0.f;
#pragma unroll
        for (int q = 0; q < P; q++) {
            a += convW[h * 915 + (E + q) * 3 + 1] * pf[i * P + q];
            a += convW[h * 915 + (E + q) * 3 + 2] * pf[(i - 1) * P + q];
        }
        c0[m * H + h] = f2bf(a);
    } else if (idx < 461536) {                     // c255: j=255, tap k=2 dropped
        int t = idx - 410736;
        int m = t / H, h = t - m * H;
        int i = m + 1;
        float a = 0.f;
#pragma unroll
        for (int q = 0; q < P; q++) {
            a += convW[h * 915 + (E + q) * 3 + 0] * pf[(254 - i) * P + q];
            a += convW[h * 915 + (E + q) * 3 + 1] * pf[(255 - i) * P + q];
        }
        c255[m * H + h] = f2bf(a);
    }
}

// ---------------- B: conv_tok GEMM via bf16 MFMA -> ct bf16[b][j][h] ----------------
// M=2048 (b,j), N=208 (h pad), K=928 (pad; zero B cols nullify A overreads).
__global__ __launch_bounds__(256) void k_conv(const unsigned short* __restrict__ tokb,
                                              const unsigned short* __restrict__ Wr3,
                                              const float* __restrict__ convB,
                                              unsigned short* __restrict__ ct) {
    int n0 = blockIdx.x * 16;
    int mg = blockIdx.y;
    int wave = threadIdx.x >> 6;
    int lane = threadIdx.x & 63;
    int quad = lane >> 4;
    int lr = lane & 15;
    int mtile = mg * 4 + wave;
    int b = mtile >> 4;
    int j0 = (mtile & 15) << 4;

    const unsigned short* pa = tokb + ((size_t)(b * 258 + j0 + lr) * 300 + quad * 8);
    const unsigned short* pb = Wr3 + ((size_t)(n0 + lr) * 928 + quad * 8);

    f32x4 acc0 = {0.f, 0.f, 0.f, 0.f};
    f32x4 acc1 = {0.f, 0.f, 0.f, 0.f};
#pragma unroll
    for (int kk = 0; kk + 1 < 29; kk += 2) {
        short8 a0 = load_a8(pa + kk * 32);
        short8 b0 = *(const short8*)(pb + kk * 32);
        acc0 = __builtin_amdgcn_mfma_f32_16x16x32_bf16(a0, b0, acc0, 0, 0, 0);
        short8 a1 = load_a8(pa + kk * 32 + 32);
        short8 b1 = *(const short8*)(pb + kk * 32 + 32);
        acc1 = __builtin_amdgcn_mfma_f32_16x16x32_bf16(a1, b1, acc1, 0, 0, 0);
    }
    {   // tail kk=28
        short8 a0 = load_a8(pa + 28 * 32);
        short8 b0 = *(const short8*)(pb + 28 * 32);
        acc0 = __builtin_amdgcn_mfma_f32_16x16x32_bf16(a0, b0, acc0, 0, 0, 0);
    }
    int h = n0 + lr;
    if (h < H) {
        float bias = convB[h];
#pragma unroll
        for (int r = 0; r < 4; r++)
            ct[(size_t)(b * 256 + j0 + quad * 4 + r) * 200 + h] = f2bf(acc0[r] + acc1[r] + bias);
    }
}

// ---------------- C: dynamic max pool (bf16 in) -> poolbf bf16[b][256][416] --------
// grid (64 pg, 8 b); 512 thr = 8 j-subs x 64 lanes (50 active, h=4*lane), 32 j each.
// bf16 b64 loads, branch-free 3-range j loop. NO occupancy pin (R6's (512,4) pin
// caused VGPR=64 -> accumulator spills -> 428 MB scratch writes). unroll 4.
__global__ __launch_bounds__(512) void k_poolA(const unsigned short* __restrict__ ct,
                                               const unsigned short* __restrict__ g,
                                               const unsigned short* __restrict__ c0,
                                               const unsigned short* __restrict__ c255,
                                               unsigned short* __restrict__ poolbf) {
    __shared__ float4 lds4[8 * 4 * 2 * 50];        // [sub][k][lr][lane] 51.2 KB
    int pg = blockIdx.x;
    int b  = blockIdx.y;
    int tid = threadIdx.x;
    int sub = tid >> 6;
    int lane = tid & 63;
    int p0 = pg * 4 + 1;                           // pivots p0..p0+3

    if (lane < 50) {
        int h = lane << 2;
        const unsigned short* ctb = ct + (size_t)b * S * H + h;
        const unsigned short* gb  = g + h;

        float4 aL0 = {0,0,0,0}, aL1 = aL0, aL2 = aL0, aL3 = aL0;
        float4 aR0 = aL0, aR1 = aL0, aR2 = aL0, aR3 = aL0;

        if (sub == 0) {                            // j = 0 special (always left)
            float4 c = bf4(*(const ushort4*)(ctb));
            int m = pg * 4;
            if (m + 0 < NI) aL0 = max4(aL0, add4(c, bf4(*(const ushort4*)(c0 + (m+0) * H + h))));
            if (m + 1 < NI) aL1 = max4(aL1, add4(c, bf4(*(const ushort4*)(c0 + (m+1) * H + h))));
            if (m + 2 < NI) aL2 = max4(aL2, add4(c, bf4(*(const ushort4*)(c0 + (m+2) * H + h))));
            if (m + 3 < NI) aL3 = max4(aL3, add4(c, bf4(*(const ushort4*)(c0 + (m+3) * H + h))));
        }
        if (sub == 7) {                            // j = 255 special (always right)
            float4 c = bf4(*(const ushort4*)(ctb + (size_t)255 * H));
            int m = pg * 4;
            if (m + 0 < NI) aR0 = max4(aR0, add4(c, bf4(*(const ushort4*)(c255 + (m+0) * H + h))));
            if (m + 1 < NI) aR1 = max4(aR1, add4(c, bf4(*(const ushort4*)(c255 + (m+1) * H + h))));
            if (m + 2 < NI) aR2 = max4(aR2, add4(c, bf4(*(const ushort4*)(c255 + (m+2) * H + h))));
            if (m + 3 < NI) aR3 = max4(aR3, add4(c, bf4(*(const ushort4*)(c255 + (m+3) * H + h))));
        }

        int js = (sub == 0) ? 1 : sub * 32;
        int je = (sub == 7) ? 254 : sub * 32 + 31;

        // rolling g rows: grk holds g[(j - p0 - k + 256)*H + h]
        float4 gr0 = bf4(*(const ushort4*)(gb + (size_t)(js - p0 + 256) * H));
        float4 gr1 = bf4(*(const ushort4*)(gb + (size_t)(js - p0 + 255) * H));
        float4 gr2 = bf4(*(const ushort4*)(gb + (size_t)(js - p0 + 254) * H));
        float4 gr3 = bf4(*(const ushort4*)(gb + (size_t)(js - p0 + 253) * H));

        int eL = (je + 1 < p0) ? (je + 1) : p0;        // [js, eL): all-left
        int mS = (js > p0) ? js : p0;                  // [mS, eM): mixed (<=4)
        int eM = (je + 1 < p0 + 4) ? (je + 1) : (p0 + 4);
        int rS = (js > p0 + 4) ? js : (p0 + 4);        // [rS, je]: all-right

#pragma unroll 4
        for (int j = js; j < eL; ++j) {
            float4 c = bf4(*(const ushort4*)(ctb + (size_t)j * H));
            aL0 = max4(aL0, add4(c, gr0));
            aL1 = max4(aL1, add4(c, gr1));
            aL2 = max4(aL2, add4(c, gr2));
            aL3 = max4(aL3, add4(c, gr3));
            gr3 = gr2; gr2 = gr1; gr1 = gr0;
            gr0 = bf4(*(const ushort4*)(gb + (size_t)(j + 1 - p0 + 256) * H));
        }
        for (int j = mS; j < eM; ++j) {                // <= 4 iterations
            float4 c = bf4(*(const ushort4*)(ctb + (size_t)j * H));
            float4 v0 = add4(c, gr0);
            float4 v1 = add4(c, gr1);
            float4 v2 = add4(c, gr2);
            float4 v3 = add4(c, gr3);
            if (j < p0)     aL0 = max4(aL0, v0); else aR0 = max4(aR0, v0);
            if (j < p0 + 1) aL1 = max4(aL1, v1); else aR1 = max4(aR1, v1);
            if (j < p0 + 2) aL2 = max4(aL2, v2); else aR2 = max4(aR2, v2);
            if (j < p0 + 3) aL3 = max4(aL3, v3); else aR3 = max4(aR3, v3);
            gr3 = gr2; gr2 = gr1; gr1 = gr0;
            gr0 = bf4(*(const ushort4*)(gb + (size_t)(j + 1 - p0 + 256) * H));
        }
#pragma unroll 4
        for (int j = rS; j <= je; ++j) {
            float4 c = bf4(*(const ushort4*)(ctb + (size_t)j * H));
            aR0 = max4(aR0, add4(c, gr0));
            aR1 = max4(aR1, add4(c, gr1));
            aR2 = max4(aR2, add4(c, gr2));
            aR3 = max4(aR3, add4(c, gr3));
            gr3 = gr2; gr2 = gr1; gr1 = gr0;
            gr0 = bf4(*(const ushort4*)(gb + (size_t)(j + 1 - p0 + 256) * H));
        }

        float4* lp = lds4 + (size_t)sub * 400 + lane;
        lp[0]   = aL0; lp[50]  = aR0;
        lp[100] = aL1; lp[150] = aR1;
        lp[200] = aL2; lp[250] = aR2;
        lp[300] = aL3; lp[350] = aR3;
    }
    __syncthreads();

    if (tid < 400) {
        int k = tid / 100;
        int r = tid - k * 100;
        int half = r / 50;
        int ln = r - half * 50;
        int slot = (k * 2 + half) * 50 + ln;
        float4 v = lds4[slot];
#pragma unroll
        for (int s2 = 1; s2 < 8; s2++) v = max4(v, lds4[s2 * 400 + slot]);
        int m = pg * 4 + k;
        if (m < NI) {
            ushort4 o;
            o.x = f2bf(v.x); o.y = f2bf(v.y); o.z = f2bf(v.z); o.w = f2bf(v.w);
            *(ushort4*)(poolbf + (size_t)(b * 256 + m + 1) * 416 + half * 200 + ln * 4) = o;
        }
    } else if (tid < 464) {                        // zero K-pad cols 400..415
        int t = tid - 400;
        int k = t >> 4, c = t & 15;
        int m = pg * 4 + k;
        if (m < NI) poolbf[(size_t)(b * 256 + m + 1) * 416 + 400 + c] = 0;
    }
}

// ---------------- D: fused FC GEMM (both K-parts) + bias + end padding -> out ------
// M=2048 (b,s), N=48 (l pad). K part0 = pool (416), part1 = llf via tokb (928).
// Rows s=0,255 are garbage in A; overridden by the pad in the epilogue.
__global__ __launch_bounds__(256) void k_fc(const unsigned short* __restrict__ poolbf,
                                            const unsigned short* __restrict__ tokb,
                                            const unsigned short* __restrict__ fcWb,
                                            const float* __restrict__ fcB,
                                            float* __restrict__ out) {
    int n0 = blockIdx.x * 16;
    int mg = blockIdx.y;
    int wave = threadIdx.x >> 6;
    int lane = threadIdx.x & 63;
    int quad = lane >> 4;
    int lr = lane & 15;
    int mtile = mg * 4 + wave;
    int b = mtile >> 4;
    int s0 = (mtile & 15) << 4;

    const unsigned short* pa0 = poolbf + ((size_t)(b * 256 + s0 + lr) * 416 + quad * 8);
    const unsigned short* pa1 = tokb + ((size_t)(b * 258 + s0 + lr) * 300 + quad * 8);
    const unsigned short* pb0 = fcWb + ((size_t)(n0 + lr) * 1344 + quad * 8);
    const unsigned short* pb1 = pb0 + 416;

    f32x4 acc0 = {0.f, 0.f, 0.f, 0.f};
    f32x4 acc1 = {0.f, 0.f, 0.f, 0.f};
    int kk = 0;
#pragma unroll 3
    for (kk = 0; kk + 1 < 13; kk += 2) {
        short8 a0 = load_a8(pa0 + kk * 32);
        short8 b0 = *(const short8*)(pb0 + kk * 32);
        acc0 = __builtin_amdgcn_mfma_f32_16x16x32_bf16(a0, b0, acc0, 0, 0, 0);
        short8 a1 = load_a8(pa0 + kk * 32 + 32);
        short8 b1 = *(const short8*)(pb0 + kk * 32 + 32);
        acc1 = __builtin_amdgcn_mfma_f32_16x16x32_bf16(a1, b1, acc1, 0, 0, 0);
    }
    {   // part0 tail kk=12
        short8 a0 = load_a8(pa0 + 12 * 32);
        short8 b0 = *(const short8*)(pb0 + 12 * 32);
        acc0 = __builtin_amdgcn_mfma_f32_16x16x32_bf16(a0, b0, acc0, 0, 0, 0);
    }
#pragma unroll 4
    for (kk = 0; kk + 1 < 29; kk += 2) {
        short8 a0 = load_a8(pa1 + kk * 32);
        short8 b0 = *(const short8*)(pb1 + kk * 32);
        acc0 = __builtin_amdgcn_mfma_f32_16x16x32_bf16(a0, b0, acc0, 0, 0, 0);
        short8 a1 = load_a8(pa1 + kk * 32 + 32);
        short8 b1 = *(const short8*)(pb1 + kk * 32 + 32);
        acc1 = __builtin_amdgcn_mfma_f32_16x16x32_bf16(a1, b1, acc1, 0, 0, 0);
    }
    {   // part1 tail kk=28
        short8 a0 = load_a8(pa1 + 28 * 32);
        short8 b0 = *(const short8*)(pb1 + 28 * 32);
        acc0 = __builtin_amdgcn_mfma_f32_16x16x32_bf16(a0, b0, acc0, 0, 0, 0);
    }

    int l = n0 + lr;
    if (l < L) {
        float bias = fcB[l];
#pragma unroll
        for (int r = 0; r < 4; r++) {
            int s = s0 + quad * 4 + r;
            float val;
            if (s == 0 || s == S - 1) val = (l == L - 1) ? 1.0f : 0.0f;
            else                      val = acc0[r] + acc1[r] + bias;
            out[(size_t)(b * 256 + s) * L + l] = val;
        }
    }
}

extern "C" void kernel_launch(void* const* d_in, const int* in_sizes, int n_in,
                              void* d_out, int out_size, void* d_ws, size_t ws_size,
                              hipStream_t stream) {
    const int*   ids      = (const int*)d_in[0];
    const float* word_emb = (const float*)d_in[1];
    const float* pf_emb   = (const float*)d_in[2];
    const float* conv_W   = (const float*)d_in[3];
    const float* conv_b   = (const float*)d_in[4];
    const float* fc_W     = (const float*)d_in[5];
    const float* fc_b     = (const float*)d_in[6];
    float* out = (float*)d_out;
    float* ws  = (float*)d_ws;

    unsigned short* tokb   = (unsigned short*)(ws + TOKB_OFF);
    unsigned short* Wr3    = (unsigned short*)(ws + WR3_OFF);
    unsigned short* fcWb   = (unsigned short*)(ws + FCWB_OFF);
    unsigned short* g      = (unsigned short*)(ws + G_OFF);
    unsigned short* c0     = (unsigned short*)(ws + C0_OFF);
    unsigned short* c255   = (unsigned short*)(ws + C255_OFF);
    unsigned short* ct     = (unsigned short*)(ws + CT_OFF);
    unsigned short* poolbf = (unsigned short*)(ws + POOLBF_OFF);

    k_init<<<GA_BLOCKS + PREP_BLOCKS, 256, 0, stream>>>(ids, word_emb, conv_W, fc_W,
                                                        pf_emb, tokb, Wr3, fcWb,
                                                        g, c0, c255);
    k_conv<<<dim3(13, 32), 256, 0, stream>>>(tokb, Wr3, conv_b, ct);
    k_poolA<<<dim3(64, 8), 512, 0, stream>>>(ct, g, c0, c255, poolbf);
    k_fc<<<dim3(3, 32), 256, 0, stream>>>(poolbf, tokb, fcWb, fc_b, out);
}

// Round 8
// 119.513 us; speedup vs baseline: 2.9458x; 1.1418x over previous
//
#include <hip/hip_runtime.h>

#define E 300
#define P 5
#define H 200
#define S 256
#define L 34
#define B 8
#define NI 254   // pivot positions i = 1..254

typedef __attribute__((ext_vector_type(8))) _Float16 half8;
typedef __attribute__((ext_vector_type(2))) _Float16 h2;
typedef __attribute__((ext_vector_type(4))) float f32x4;

// ws layout (float units; all f16 arrays, same byte sizes as bf16 rounds)
#define TOKB_OFF   0            // tokb f16[8][258][300] (+slack)
#define TOKB_FL    309632
#define WR3_OFF    309632       // Wr3[208][928] f16
#define WR3_FL     96512
#define FCWB_OFF   406144       // fcWb[48][1344] f16
#define FCWB_FL    32256
#define G_OFF      438400       // g f16[512][200]
#define G_FL       51200
#define C0_OFF     489600       // c0 f16[254][200]
#define C0_FL      25400
#define C255_OFF   515000       // c255 f16[254][200]
#define C255_FL    25400
#define CT_OFF     540400       // ct f16[b][j][h]
#define CT_FL      204800
#define POOLF_OFF  745200       // poolf f16[b][256][416]
#define POOLF_FL   425984
// total 1,171,184 floats = 4.7 MB

__device__ __forceinline__ unsigned short f2h(float f) {
    _Float16 h = (_Float16)f;               // RNE
    unsigned short u; __builtin_memcpy(&u, &h, 2);
    return u;
}
__device__ __forceinline__ h2 u2h2(unsigned u) {
    h2 h; __builtin_memcpy(&h, &u, 4); return h;
}
__device__ __forceinline__ unsigned h2u(h2 h) {
    unsigned u; __builtin_memcpy(&u, &h, 4); return u;
}
__device__ __forceinline__ h2 hmax2(h2 a, h2 b) {
    return __builtin_elementwise_max(a, b);  // v_pk_max_f16
}
__device__ __forceinline__ half8 load_h8(const unsigned short* p) {
    half8 r;
    ((ushort4*)&r)[0] = *(const ushort4*)p;  // rows are 8B-aligned
    ((ushort4*)&r)[1] = *(const ushort4*)(p + 4);
    return r;
}

#define GA_BLOCKS 605    // gather part: 154800 groups
#define PREP_BLOCKS 1803 // prep part: 461536 items

// ---------------- A: fused init = embedding gather + weight repacks + pf tables ----
__global__ __launch_bounds__(256) void k_init(const int* __restrict__ ids,
                                              const float* __restrict__ we,
                                              const float* __restrict__ convW,
                                              const float* __restrict__ fcW,
                                              const float* __restrict__ pf,
                                              unsigned short* __restrict__ tokb,
                                              unsigned short* __restrict__ Wr3,
                                              unsigned short* __restrict__ fcWb,
                                              unsigned short* __restrict__ g,
                                              unsigned short* __restrict__ c0,
                                              unsigned short* __restrict__ c255) {
    if (blockIdx.x < GA_BLOCKS) {
        // tokb f16[b][258][300], rows 0 & 257 zero
        int idx = blockIdx.x * 256 + threadIdx.x;
        const int total = B * 258 * 75;
        if (idx >= total) return;
        int row = idx / 75;
        int col = idx - row * 75;
        int b = row / 258;
        int r = row - b * 258;
        float4 v = make_float4(0.f, 0.f, 0.f, 0.f);
        if (r >= 1 && r <= 256) {
            int id = ids[b * S + (r - 1)];
            v = ((const float4*)we)[(size_t)id * 75 + col];
        }
        ushort4 o;
        o.x = f2h(v.x); o.y = f2h(v.y); o.z = f2h(v.z); o.w = f2h(v.w);
        *(ushort4*)(tokb + (size_t)row * 300 + col * 4) = o;
        return;
    }
    int idx = (blockIdx.x - GA_BLOCKS) * 256 + threadIdx.x;
    if (idx < 193024) {                            // Wr3: 208x928, Wr3[h][r*300+e]
        int hh = idx / 928, kk = idx - hh * 928;
        float v = 0.f;
        if (hh < H && kk < 900) {
            int r = kk / 300, e = kk - r * 300;
            v = convW[hh * 915 + e * 3 + r];
        }
        Wr3[idx] = f2h(v);
    } else if (idx < 257536) {                     // fcWb: 48x1344
        int t = idx - 193024;
        int l = t / 1344, c = t - l * 1344;
        float v = 0.f;
        if (l < L) {
            if (c < 400) v = fcW[l * 1300 + c];
            else if (c >= 416 && c < 1316) v = fcW[l * 1300 + 400 + (c - 416)];
        }
        fcWb[t] = f2h(v);
    } else if (idx < 359936) {                     // g[t2][h], t2 = (j-i)+256
        int t = idx - 257536;
        int t2 = t / H, h = t - t2 * H;
        int d = t2 - 256;
        float a = 0.f;
#pragma unroll
        for (int k = 0; k < 3; k++) {
            int r = d + k - 1; r = (r < 0) ? -r : r; if (r > 255) r = 255;
#pragma unroll
            for (int q = 0; q < P; q++)
                a += convW[h * 915 + (E + q) * 3 + k] * pf[r * P + q];
        }
        g[t] = f2h(a);
    } else if (idx < 410736) {                     // c0: j=0, tap k=0 dropped
        int t = idx - 359936;
        int m = t / H, h = t - m * H;
        int i = m + 1;
        float a = 0.f;
#pragma unroll
        for (int q = 0; q < P; q++) {
            a += convW[h * 915 + (E + q) * 3 + 1] * pf[i * P + q];
            a += convW[h * 915 + (E + q) * 3 + 2] * pf[(i - 1) * P + q];
        }
        c0[m * H + h] = f2h(a);
    } else if (idx < 461536) {                     // c255: j=255, tap k=2 dropped
        int t = idx - 410736;
        int m = t / H, h = t - m * H;
        int i = m + 1;
        float a = 0.f;
#pragma unroll
        for (int q = 0; q < P; q++) {
            a += convW[h * 915 + (E + q) * 3 + 0] * pf[(254 - i) * P + q];
            a += convW[h * 915 + (E + q) * 3 + 1] * pf[(255 - i) * P + q];
        }
        c255[m * H + h] = f2h(a);
    }
}

// ---------------- B: conv_tok GEMM via f16 MFMA -> ct f16[b][j][h] ----------------
// M=2048 (b,j), N=208 (h pad), K=928 (pad; zero B cols nullify A overreads).
__global__ __launch_bounds__(256) void k_conv(const unsigned short* __restrict__ tokb,
                                              const unsigned short* __restrict__ Wr3,
                                              const float* __restrict__ convB,
                                              unsigned short* __restrict__ ct) {
    int n0 = blockIdx.x * 16;
    int mg = blockIdx.y;
    int wave = threadIdx.x >> 6;
    int lane = threadIdx.x & 63;
    int quad = lane >> 4;
    int lr = lane & 15;
    int mtile = mg * 4 + wave;
    int b = mtile >> 4;
    int j0 = (mtile & 15) << 4;

    const unsigned short* pa = tokb + ((size_t)(b * 258 + j0 + lr) * 300 + quad * 8);
    const unsigned short* pb = Wr3 + ((size_t)(n0 + lr) * 928 + quad * 8);

    f32x4 acc0 = {0.f, 0.f, 0.f, 0.f};
    f32x4 acc1 = {0.f, 0.f, 0.f, 0.f};
#pragma unroll
    for (int kk = 0; kk + 1 < 29; kk += 2) {
        half8 a0 = load_h8(pa + kk * 32);
        half8 b0 = load_h8(pb + kk * 32);
        acc0 = __builtin_amdgcn_mfma_f32_16x16x32_f16(a0, b0, acc0, 0, 0, 0);
        half8 a1 = load_h8(pa + kk * 32 + 32);
        half8 b1 = load_h8(pb + kk * 32 + 32);
        acc1 = __builtin_amdgcn_mfma_f32_16x16x32_f16(a1, b1, acc1, 0, 0, 0);
    }
    {   // tail kk=28
        half8 a0 = load_h8(pa + 28 * 32);
        half8 b0 = load_h8(pb + 28 * 32);
        acc0 = __builtin_amdgcn_mfma_f32_16x16x32_f16(a0, b0, acc0, 0, 0, 0);
    }
    int h = n0 + lr;
    if (h < H) {
        float bias = convB[h];
#pragma unroll
        for (int r = 0; r < 4; r++)
            ct[(size_t)(b * 256 + j0 + quad * 4 + r) * 200 + h] = f2h(acc0[r] + acc1[r] + bias);
    }
}

// ---------------- C: dynamic max pool, packed-f16 VALU -> poolf f16[b][256][416] ----
// grid (64 pg, 8 b); 512 thr = 8 j-subs x 64 lanes (50 active, h=4*lane), 32 j each.
// Per j: 2x b64 loads + 16 v_pk ops (4 pivots x 4 h) + rolling movs. No f32 converts.
__global__ __launch_bounds__(512) void k_poolA(const unsigned short* __restrict__ ct,
                                               const unsigned short* __restrict__ g,
                                               const unsigned short* __restrict__ c0,
                                               const unsigned short* __restrict__ c255,
                                               unsigned short* __restrict__ poolf) {
    __shared__ uint2 lds2[8 * 4 * 2 * 50];         // [sub][k][lr][lane], 4 f16 each; 25.6 KB
    int pg = blockIdx.x;
    int b  = blockIdx.y;
    int tid = threadIdx.x;
    int sub = tid >> 6;
    int lane = tid & 63;
    int p0 = pg * 4 + 1;                           // pivots p0..p0+3

    if (lane < 50) {
        int h = lane << 2;
        const unsigned short* ctb = ct + (size_t)b * S * H + h;
        const unsigned short* gb  = g + h;

        h2 z = {(_Float16)0, (_Float16)0};
        h2 aL0a=z, aL0b=z, aL1a=z, aL1b=z, aL2a=z, aL2b=z, aL3a=z, aL3b=z;
        h2 aR0a=z, aR0b=z, aR1a=z, aR1b=z, aR2a=z, aR2b=z, aR3a=z, aR3b=z;

        if (sub == 0) {                            // j = 0 special (always left)
            uint2 cu = *(const uint2*)ctb;
            h2 ca = u2h2(cu.x), cb = u2h2(cu.y);
            int m = pg * 4;
            if (m + 0 < NI) { uint2 t = *(const uint2*)(c0 + (m+0) * H + h);
                aL0a = hmax2(aL0a, ca + u2h2(t.x)); aL0b = hmax2(aL0b, cb + u2h2(t.y)); }
            if (m + 1 < NI) { uint2 t = *(const uint2*)(c0 + (m+1) * H + h);
                aL1a = hmax2(aL1a, ca + u2h2(t.x)); aL1b = hmax2(aL1b, cb + u2h2(t.y)); }
            if (m + 2 < NI) { uint2 t = *(const uint2*)(c0 + (m+2) * H + h);
                aL2a = hmax2(aL2a, ca + u2h2(t.x)); aL2b = hmax2(aL2b, cb + u2h2(t.y)); }
            if (m + 3 < NI) { uint2 t = *(const uint2*)(c0 + (m+3) * H + h);
                aL3a = hmax2(aL3a, ca + u2h2(t.x)); aL3b = hmax2(aL3b, cb + u2h2(t.y)); }
        }
        if (sub == 7) {                            // j = 255 special (always right)
            uint2 cu = *(const uint2*)(ctb + (size_t)255 * H);
            h2 ca = u2h2(cu.x), cb = u2h2(cu.y);
            int m = pg * 4;
            if (m + 0 < NI) { uint2 t = *(const uint2*)(c255 + (m+0) * H + h);
                aR0a = hmax2(aR0a, ca + u2h2(t.x)); aR0b = hmax2(aR0b, cb + u2h2(t.y)); }
            if (m + 1 < NI) { uint2 t = *(const uint2*)(c255 + (m+1) * H + h);
                aR1a = hmax2(aR1a, ca + u2h2(t.x)); aR1b = hmax2(aR1b, cb + u2h2(t.y)); }
            if (m + 2 < NI) { uint2 t = *(const uint2*)(c255 + (m+2) * H + h);
                aR2a = hmax2(aR2a, ca + u2h2(t.x)); aR2b = hmax2(aR2b, cb + u2h2(t.y)); }
            if (m + 3 < NI) { uint2 t = *(const uint2*)(c255 + (m+3) * H + h);
                aR3a = hmax2(aR3a, ca + u2h2(t.x)); aR3b = hmax2(aR3b, cb + u2h2(t.y)); }
        }

        int js = (sub == 0) ? 1 : sub * 32;
        int je = (sub == 7) ? 254 : sub * 32 + 31;

        // rolling g rows: grk holds g[(j - p0 - k + 256)*H + h] as 2x h2
        uint2 gu;
        gu = *(const uint2*)(gb + (size_t)(js - p0 + 256) * H); h2 gr0a = u2h2(gu.x), gr0b = u2h2(gu.y);
        gu = *(const uint2*)(gb + (size_t)(js - p0 + 255) * H); h2 gr1a = u2h2(gu.x), gr1b = u2h2(gu.y);
        gu = *(const uint2*)(gb + (size_t)(js - p0 + 254) * H); h2 gr2a = u2h2(gu.x), gr2b = u2h2(gu.y);
        gu = *(const uint2*)(gb + (size_t)(js - p0 + 253) * H); h2 gr3a = u2h2(gu.x), gr3b = u2h2(gu.y);

        int eL = (je + 1 < p0) ? (je + 1) : p0;        // [js, eL): all-left
        int mS = (js > p0) ? js : p0;                  // [mS, eM): mixed (<=4)
        int eM = (je + 1 < p0 + 4) ? (je + 1) : (p0 + 4);
        int rS = (js > p0 + 4) ? js : (p0 + 4);        // [rS, je]: all-right

#pragma unroll 4
        for (int j = js; j < eL; ++j) {
            uint2 cu = *(const uint2*)(ctb + (size_t)j * H);
            h2 ca = u2h2(cu.x), cb = u2h2(cu.y);
            aL0a = hmax2(aL0a, ca + gr0a); aL0b = hmax2(aL0b, cb + gr0b);
            aL1a = hmax2(aL1a, ca + gr1a); aL1b = hmax2(aL1b, cb + gr1b);
            aL2a = hmax2(aL2a, ca + gr2a); aL2b = hmax2(aL2b, cb + gr2b);
            aL3a = hmax2(aL3a, ca + gr3a); aL3b = hmax2(aL3b, cb + gr3b);
            gr3a = gr2a; gr3b = gr2b; gr2a = gr1a; gr2b = gr1b; gr1a = gr0a; gr1b = gr0b;
            uint2 gn = *(const uint2*)(gb + (size_t)(j + 1 - p0 + 256) * H);
            gr0a = u2h2(gn.x); gr0b = u2h2(gn.y);
        }
        for (int j = mS; j < eM; ++j) {                // <= 4 iterations
            uint2 cu = *(const uint2*)(ctb + (size_t)j * H);
            h2 ca = u2h2(cu.x), cb = u2h2(cu.y);
            h2 v0a = ca + gr0a, v0b = cb + gr0b;
            h2 v1a = ca + gr1a, v1b = cb + gr1b;
            h2 v2a = ca + gr2a, v2b = cb + gr2b;
            h2 v3a = ca + gr3a, v3b = cb + gr3b;
            if (j < p0)     { aL0a = hmax2(aL0a, v0a); aL0b = hmax2(aL0b, v0b); }
            else            { aR0a = hmax2(aR0a, v0a); aR0b = hmax2(aR0b, v0b); }
            if (j < p0 + 1) { aL1a = hmax2(aL1a, v1a); aL1b = hmax2(aL1b, v1b); }
            else            { aR1a = hmax2(aR1a, v1a); aR1b = hmax2(aR1b, v1b); }
            if (j < p0 + 2) { aL2a = hmax2(aL2a, v2a); aL2b = hmax2(aL2b, v2b); }
            else            { aR2a = hmax2(aR2a, v2a); aR2b = hmax2(aR2b, v2b); }
            if (j < p0 + 3) { aL3a = hmax2(aL3a, v3a); aL3b = hmax2(aL3b, v3b); }
            else            { aR3a = hmax2(aR3a, v3a); aR3b = hmax2(aR3b, v3b); }
            gr3a = gr2a; gr3b = gr2b; gr2a = gr1a; gr2b = gr1b; gr1a = gr0a; gr1b = gr0b;
            uint2 gn = *(const uint2*)(gb + (size_t)(j + 1 - p0 + 256) * H);
            gr0a = u2h2(gn.x); gr0b = u2h2(gn.y);
        }
#pragma unroll 4
        for (int j = rS; j <= je; ++j) {
            uint2 cu = *(const uint2*)(ctb + (size_t)j * H);
            h2 ca = u2h2(cu.x), cb = u2h2(cu.y);
            aR0a = hmax2(aR0a, ca + gr0a); aR0b = hmax2(aR0b, cb + gr0b);
            aR1a = hmax2(aR1a, ca + gr1a); aR1b = hmax2(aR1b, cb + gr1b);
            aR2a = hmax2(aR2a, ca + gr2a); aR2b = hmax2(aR2b, cb + gr2b);
            aR3a = hmax2(aR3a, ca + gr3a); aR3b = hmax2(aR3b, cb + gr3b);
            gr3a = gr2a; gr3b = gr2b; gr2a = gr1a; gr2b = gr1b; gr1a = gr0a; gr1b = gr0b;
            uint2 gn = *(const uint2*)(gb + (size_t)(j + 1 - p0 + 256) * H);
            gr0a = u2h2(gn.x); gr0b = u2h2(gn.y);
        }

        uint2* lp = lds2 + (size_t)sub * 400 + lane;
        lp[0]   = make_uint2(h2u(aL0a), h2u(aL0b)); lp[50]  = make_uint2(h2u(aR0a), h2u(aR0b));
        lp[100] = make_uint2(h2u(aL1a), h2u(aL1b)); lp[150] = make_uint2(h2u(aR1a), h2u(aR1b));
        lp[200] = make_uint2(h2u(aL2a), h2u(aL2b)); lp[250] = make_uint2(h2u(aR2a), h2u(aR2b));
        lp[300] = make_uint2(h2u(aL3a), h2u(aL3b)); lp[350] = make_uint2(h2u(aR3a), h2u(aR3b));
    }
    __syncthreads();

    if (tid < 400) {
        int k = tid / 100;
        int r = tid - k * 100;
        int hf = r / 50;
        int ln = r - hf * 50;
        int slot = (k * 2 + hf) * 50 + ln;
        uint2 v = lds2[slot];
        h2 va = u2h2(v.x), vb = u2h2(v.y);
#pragma unroll
        for (int s2 = 1; s2 < 8; s2++) {
            uint2 w = lds2[s2 * 400 + slot];
            va = hmax2(va, u2h2(w.x));
            vb = hmax2(vb, u2h2(w.y));
        }
        int m = pg * 4 + k;
        if (m < NI)
            *(uint2*)(poolf + (size_t)(b * 256 + m + 1) * 416 + hf * 200 + ln * 4)
                = make_uint2(h2u(va), h2u(vb));
    } else if (tid < 464) {                        // zero K-pad cols 400..415
        int t = tid - 400;
        int k = t >> 4, c = t & 15;
        int m = pg * 4 + k;
        if (m < NI) poolf[(size_t)(b * 256 + m + 1) * 416 + 400 + c] = 0;
    }
}

// ---------------- D: fused FC GEMM (both K-parts) + bias + end padding -> out ------
// M=2048 (b,s), N=48 (l pad). K part0 = pool (416), part1 = llf via tokb (928).
// Rows s=0,255 are garbage (finite f16 poison) in A; overridden in epilogue.
__global__ __launch_bounds__(256) void k_fc(const unsigned short* __restrict__ poolf,
                                            const unsigned short* __restrict__ tokb,
                                            const unsigned short* __restrict__ fcWb,
                                            const float* __restrict__ fcB,
                                            float* __restrict__ out) {
    int n0 = blockIdx.x * 16;
    int mg = blockIdx.y;
    int wave = threadIdx.x >> 6;
    int lane = threadIdx.x & 63;
    int quad = lane >> 4;
    int lr = lane & 15;
    int mtile = mg * 4 + wave;
    int b = mtile >> 4;
    int s0 = (mtile & 15) << 4;

    const unsigned short* pa0 = poolf + ((size_t)(b * 256 + s0 + lr) * 416 + quad * 8);
    const unsigned short* pa1 = tokb + ((size_t)(b * 258 + s0 + lr) * 300 + quad * 8);
    const unsigned short* pb0 = fcWb + ((size_t)(n0 + lr) * 1344 + quad * 8);
    const unsigned short* pb1 = pb0 + 416;

    f32x4 acc0 = {0.f, 0.f, 0.f, 0.f};
    f32x4 acc1 = {0.f, 0.f, 0.f, 0.f};
    int kk = 0;
#pragma unroll 3
    for (kk = 0; kk + 1 < 13; kk += 2) {
        half8 a0 = load_h8(pa0 + kk * 32);
        half8 b0 = load_h8(pb0 + kk * 32);
        acc0 = __builtin_amdgcn_mfma_f32_16x16x32_f16(a0, b0, acc0, 0, 0, 0);
        half8 a1 = load_h8(pa0 + kk * 32 + 32);
        half8 b1 = load_h8(pb0 + kk * 32 + 32);
        acc1 = __builtin_amdgcn_mfma_f32_16x16x32_f16(a1, b1, acc1, 0, 0, 0);
    }
    {   // part0 tail kk=12
        half8 a0 = load_h8(pa0 + 12 * 32);
        half8 b0 = load_h8(pb0 + 12 * 32);
        acc0 = __builtin_amdgcn_mfma_f32_16x16x32_f16(a0, b0, acc0, 0, 0, 0);
    }
#pragma unroll 4
    for (kk = 0; kk + 1 < 29; kk += 2) {
        half8 a0 = load_h8(pa1 + kk * 32);
        half8 b0 = load_h8(pb1 + kk * 32);
        acc0 = __builtin_amdgcn_mfma_f32_16x16x32_f16(a0, b0, acc0, 0, 0, 0);
        half8 a1 = load_h8(pa1 + kk * 32 + 32);
        half8 b1 = load_h8(pb1 + kk * 32 + 32);
        acc1 = __builtin_amdgcn_mfma_f32_16x16x32_f16(a1, b1, acc1, 0, 0, 0);
    }
    {   // part1 tail kk=28
        half8 a0 = load_h8(pa1 + 28 * 32);
        half8 b0 = load_h8(pb1 + 28 * 32);
        acc0 = __builtin_amdgcn_mfma_f32_16x16x32_f16(a0, b0, acc0, 0, 0, 0);
    }

    int l = n0 + lr;
    if (l < L) {
        float bias = fcB[l];
#pragma unroll
        for (int r = 0; r < 4; r++) {
            int s = s0 + quad * 4 + r;
            float val;
            if (s == 0 || s == S - 1) val = (l == L - 1) ? 1.0f : 0.0f;
            else                      val = acc0[r] + acc1[r] + bias;
            out[(size_t)(b * 256 + s) * L + l] = val;
        }
    }
}

extern "C" void kernel_launch(void* const* d_in, const int* in_sizes, int n_in,
                              void* d_out, int out_size, void* d_ws, size_t ws_size,
                              hipStream_t stream) {
    const int*   ids      = (const int*)d_in[0];
    const float* word_emb = (const float*)d_in[1];
    const float* pf_emb   = (const float*)d_in[2];
    const float* conv_W   = (const float*)d_in[3];
    const float* conv_b   = (const float*)d_in[4];
    const float* fc_W     = (const float*)d_in[5];
    const float* fc_b     = (const float*)d_in[6];
    float* out = (float*)d_out;
    float* ws  = (float*)d_ws;

    unsigned short* tokb  = (unsigned short*)(ws + TOKB_OFF);
    unsigned short* Wr3   = (unsigned short*)(ws + WR3_OFF);
    unsigned short* fcWb  = (unsigned short*)(ws + FCWB_OFF);
    unsigned short* g     = (unsigned short*)(ws + G_OFF);
    unsigned short* c0    = (unsigned short*)(ws + C0_OFF);
    unsigned short* c255  = (unsigned short*)(ws + C255_OFF);
    unsigned short* ct    = (unsigned short*)(ws + CT_OFF);
    unsigned short* poolf = (unsigned short*)(ws + POOLF_OFF);

    k_init<<<GA_BLOCKS + PREP_BLOCKS, 256, 0, stream>>>(ids, word_emb, conv_W, fc_W,
                                                        pf_emb, tokb, Wr3, fcWb,
                                                        g, c0, c255);
    k_conv<<<dim3(13, 32), 256, 0, stream>>>(tokb, Wr3, conv_b, ct);
    k_poolA<<<dim3(64, 8), 512, 0, stream>>>(ct, g, c0, c255, poolf);
    k_fc<<<dim3(3, 32), 256, 0, stream>>>(poolf, tokb, fcWb, fc_b, out);
}

// Round 9
// 116.907 us; speedup vs baseline: 3.0115x; 1.0223x over previous
//
#include <hip/hip_runtime.h>

#define E 300
#define P 5
#define H 200
#define S 256
#define L 34
#define B 8
#define NI 254   // pivot positions i = 1..254

typedef __attribute__((ext_vector_type(8))) _Float16 half8;
typedef __attribute__((ext_vector_type(2))) _Float16 h2;
typedef __attribute__((ext_vector_type(4))) float f32x4;

// ws layout (float units; all f16 arrays)
#define TOKB_OFF   0            // tokb f16[8][258][300] (+slack)
#define TOKB_FL    309632
#define WR3_OFF    309632       // Wr3[208][928] f16
#define WR3_FL     96512
#define FCWB_OFF   406144       // fcWb[48][1344] f16
#define FCWB_FL    32256
#define G_OFF      438400       // g f16[512][200]
#define G_FL       51200
#define C0_OFF     489600       // c0 f16[254][200]
#define C0_FL      25400
#define C255_OFF   515000       // c255 f16[254][200]
#define C255_FL    25400
#define CT_OFF     540400       // ct f16[b][j][h]
#define CT_FL      204800
#define POOLF_OFF  745200       // poolf f16[b][256][416]
#define POOLF_FL   425984
// total 1,171,184 floats = 4.7 MB

__device__ __forceinline__ unsigned short f2h(float f) {
    _Float16 h = (_Float16)f;               // RNE
    unsigned short u; __builtin_memcpy(&u, &h, 2);
    return u;
}
__device__ __forceinline__ h2 u2h2(unsigned u) {
    h2 h; __builtin_memcpy(&h, &u, 4); return h;
}
__device__ __forceinline__ unsigned h2u(h2 h) {
    unsigned u; __builtin_memcpy(&u, &h, 4); return u;
}
__device__ __forceinline__ h2 hmax2(h2 a, h2 b) {
    return __builtin_elementwise_max(a, b);  // v_pk_max_f16
}
__device__ __forceinline__ half8 load_h8(const unsigned short* p) {
    half8 r;
    ((ushort4*)&r)[0] = *(const ushort4*)p;  // rows are 8B-aligned
    ((ushort4*)&r)[1] = *(const ushort4*)(p + 4);
    return r;
}

#define GA_BLOCKS 605    // gather part: 154800 groups
#define PREP_BLOCKS 1803 // prep part: 461536 items

// ---------------- A: fused init = embedding gather + weight repacks + pf tables ----
__global__ __launch_bounds__(256) void k_init(const int* __restrict__ ids,
                                              const float* __restrict__ we,
                                              const float* __restrict__ convW,
                                              const float* __restrict__ fcW,
                                              const float* __restrict__ pf,
                                              unsigned short* __restrict__ tokb,
                                              unsigned short* __restrict__ Wr3,
                                              unsigned short* __restrict__ fcWb,
                                              unsigned short* __restrict__ g,
                                              unsigned short* __restrict__ c0,
                                              unsigned short* __restrict__ c255) {
    if (blockIdx.x < GA_BLOCKS) {
        // tokb f16[b][258][300], rows 0 & 257 zero
        int idx = blockIdx.x * 256 + threadIdx.x;
        const int total = B * 258 * 75;
        if (idx >= total) return;
        int row = idx / 75;
        int col = idx - row * 75;
        int b = row / 258;
        int r = row - b * 258;
        float4 v = make_float4(0.f, 0.f, 0.f, 0.f);
        if (r >= 1 && r <= 256) {
            int id = ids[b * S + (r - 1)];
            v = ((const float4*)we)[(size_t)id * 75 + col];
        }
        ushort4 o;
        o.x = f2h(v.x); o.y = f2h(v.y); o.z = f2h(v.z); o.w = f2h(v.w);
        *(ushort4*)(tokb + (size_t)row * 300 + col * 4) = o;
        return;
    }
    int idx = (blockIdx.x - GA_BLOCKS) * 256 + threadIdx.x;
    if (idx < 193024) {                            // Wr3: 208x928, Wr3[h][r*300+e]
        int hh = idx / 928, kk = idx - hh * 928;
        float v = 0.f;
        if (hh < H && kk < 900) {
            int r = kk / 300, e = kk - r * 300;
            v = convW[hh * 915 + e * 3 + r];
        }
        Wr3[idx] = f2h(v);
    } else if (idx < 257536) {                     // fcWb: 48x1344
        int t = idx - 193024;
        int l = t / 1344, c = t - l * 1344;
        float v = 0.f;
        if (l < L) {
            if (c < 400) v = fcW[l * 1300 + c];
            else if (c >= 416 && c < 1316) v = fcW[l * 1300 + 400 + (c - 416)];
        }
        fcWb[t] = f2h(v);
    } else if (idx < 359936) {                     // g[t2][h], t2 = (j-i)+256
        int t = idx - 257536;
        int t2 = t / H, h = t - t2 * H;
        int d = t2 - 256;
        float a = 0.f;
#pragma unroll
        for (int k = 0; k < 3; k++) {
            int r = d + k - 1; r = (r < 0) ? -r : r; if (r > 255) r = 255;
#pragma unroll
            for (int q = 0; q < P; q++)
                a += convW[h * 915 + (E + q) * 3 + k] * pf[r * P + q];
        }
        g[t] = f2h(a);
    } else if (idx < 410736) {                     // c0: j=0, tap k=0 dropped
        int t = idx - 359936;
        int m = t / H, h = t - m * H;
        int i = m + 1;
        float a = 0.f;
#pragma unroll
        for (int q = 0; q < P; q++) {
            a += convW[h * 915 + (E + q) * 3 + 1] * pf[i * P + q];
            a += convW[h * 915 + (E + q) * 3 + 2] * pf[(i - 1) * P + q];
        }
        c0[m * H + h] = f2h(a);
    } else if (idx < 461536) {                     // c255: j=255, tap k=2 dropped
        int t = idx - 410736;
        int m = t / H, h = t - m * H;
        int i = m + 1;
        float a = 0.f;
#pragma unroll
        for (int q = 0; q < P; q++) {
            a += convW[h * 915 + (E + q) * 3 + 0] * pf[(254 - i) * P + q];
            a += convW[h * 915 + (E + q) * 3 + 1] * pf[(255 - i) * P + q];
        }
        c255[m * H + h] = f2h(a);
    }
}

// ---------------- B: conv_tok GEMM, K-split x2 -> ct f16[b][j][h] ----------------
// M=2048 (b,j), N=208, K=928. 512 thr = 8 waves = 4 mtiles x 2 K-halves
// (14/15 MFMA each, half the serial chain); partner combine via 4KB LDS.
__global__ __launch_bounds__(512) void k_conv(const unsigned short* __restrict__ tokb,
                                              const unsigned short* __restrict__ Wr3,
                                              const float* __restrict__ convB,
                                              unsigned short* __restrict__ ct) {
    __shared__ float4 cld[4 * 64];                 // [mt][lane] 4 KB
    int n0 = blockIdx.x * 16;
    int mg = blockIdx.y;
    int tid = threadIdx.x;
    int wave = tid >> 6;
    int lane = tid & 63;
    int mt = wave & 3;
    int kh = wave >> 2;
    int quad = lane >> 4;
    int lr = lane & 15;
    int mtile = mg * 4 + mt;
    int b = mtile >> 4;
    int j0 = (mtile & 15) << 4;

    const unsigned short* pa = tokb + ((size_t)(b * 258 + j0 + lr) * 300 + quad * 8);
    const unsigned short* pb = Wr3 + ((size_t)(n0 + lr) * 928 + quad * 8);

    f32x4 acc0 = {0.f, 0.f, 0.f, 0.f};
    f32x4 acc1 = {0.f, 0.f, 0.f, 0.f};
    if (kh == 0) {
#pragma unroll
        for (int kk = 0; kk < 14; kk += 2) {       // kk 0..13
            half8 a0 = load_h8(pa + kk * 32);
            half8 b0 = load_h8(pb + kk * 32);
            acc0 = __builtin_amdgcn_mfma_f32_16x16x32_f16(a0, b0, acc0, 0, 0, 0);
            half8 a1 = load_h8(pa + kk * 32 + 32);
            half8 b1 = load_h8(pb + kk * 32 + 32);
            acc1 = __builtin_amdgcn_mfma_f32_16x16x32_f16(a1, b1, acc1, 0, 0, 0);
        }
    } else {
#pragma unroll
        for (int kk = 14; kk + 1 < 29; kk += 2) {  // kk 14..27
            half8 a0 = load_h8(pa + kk * 32);
            half8 b0 = load_h8(pb + kk * 32);
            acc0 = __builtin_amdgcn_mfma_f32_16x16x32_f16(a0, b0, acc0, 0, 0, 0);
            half8 a1 = load_h8(pa + kk * 32 + 32);
            half8 b1 = load_h8(pb + kk * 32 + 32);
            acc1 = __builtin_amdgcn_mfma_f32_16x16x32_f16(a1, b1, acc1, 0, 0, 0);
        }
        {   // tail kk=28
            half8 a0 = load_h8(pa + 28 * 32);
            half8 b0 = load_h8(pb + 28 * 32);
            acc0 = __builtin_amdgcn_mfma_f32_16x16x32_f16(a0, b0, acc0, 0, 0, 0);
        }
    }
    f32x4 accw = acc0 + acc1;
    if (kh == 1) {
        cld[mt * 64 + lane] = make_float4(accw[0], accw[1], accw[2], accw[3]);
    }
    __syncthreads();
    if (kh == 0) {
        float4 p = cld[mt * 64 + lane];
        int h = n0 + lr;
        if (h < H) {
            float bias = convB[h];
            ct[(size_t)(b * 256 + j0 + quad * 4 + 0) * 200 + h] = f2h(accw[0] + p.x + bias);
            ct[(size_t)(b * 256 + j0 + quad * 4 + 1) * 200 + h] = f2h(accw[1] + p.y + bias);
            ct[(size_t)(b * 256 + j0 + quad * 4 + 2) * 200 + h] = f2h(accw[2] + p.z + bias);
            ct[(size_t)(b * 256 + j0 + quad * 4 + 3) * 200 + h] = f2h(accw[3] + p.w + bias);
        }
    }
}

// ---------------- C: dynamic max pool, packed-f16 VALU -> poolf f16[b][256][416] ----
// grid (64 pg, 8 b); 512 thr = 8 j-subs x 64 lanes (50 active, h=4*lane), 32 j each.
__global__ __launch_bounds__(512) void k_poolA(const unsigned short* __restrict__ ct,
                                               const unsigned short* __restrict__ g,
                                               const unsigned short* __restrict__ c0,
                                               const unsigned short* __restrict__ c255,
                                               unsigned short* __restrict__ poolf) {
    __shared__ uint2 lds2[8 * 4 * 2 * 50];         // [sub][k][lr][lane], 4 f16 each; 25.6 KB
    int pg = blockIdx.x;
    int b  = blockIdx.y;
    int tid = threadIdx.x;
    int sub = tid >> 6;
    int lane = tid & 63;
    int p0 = pg * 4 + 1;                           // pivots p0..p0+3

    if (lane < 50) {
        int h = lane << 2;
        const unsigned short* ctb = ct + (size_t)b * S * H + h;
        const unsigned short* gb  = g + h;

        h2 z = {(_Float16)0, (_Float16)0};
        h2 aL0a=z, aL0b=z, aL1a=z, aL1b=z, aL2a=z, aL2b=z, aL3a=z, aL3b=z;
        h2 aR0a=z, aR0b=z, aR1a=z, aR1b=z, aR2a=z, aR2b=z, aR3a=z, aR3b=z;

        if (sub == 0) {                            // j = 0 special (always left)
            uint2 cu = *(const uint2*)ctb;
            h2 ca = u2h2(cu.x), cb = u2h2(cu.y);
            int m = pg * 4;
            if (m + 0 < NI) { uint2 t = *(const uint2*)(c0 + (m+0) * H + h);
                aL0a = hmax2(aL0a, ca + u2h2(t.x)); aL0b = hmax2(aL0b, cb + u2h2(t.y)); }
            if (m + 1 < NI) { uint2 t = *(const uint2*)(c0 + (m+1) * H + h);
                aL1a = hmax2(aL1a, ca + u2h2(t.x)); aL1b = hmax2(aL1b, cb + u2h2(t.y)); }
            if (m + 2 < NI) { uint2 t = *(const uint2*)(c0 + (m+2) * H + h);
                aL2a = hmax2(aL2a, ca + u2h2(t.x)); aL2b = hmax2(aL2b, cb + u2h2(t.y)); }
            if (m + 3 < NI) { uint2 t = *(const uint2*)(c0 + (m+3) * H + h);
                aL3a = hmax2(aL3a, ca + u2h2(t.x)); aL3b = hmax2(aL3b, cb + u2h2(t.y)); }
        }
        if (sub == 7) {                            // j = 255 special (always right)
            uint2 cu = *(const uint2*)(ctb + (size_t)255 * H);
            h2 ca = u2h2(cu.x), cb = u2h2(cu.y);
            int m = pg * 4;
            if (m + 0 < NI) { uint2 t = *(const uint2*)(c255 + (m+0) * H + h);
                aR0a = hmax2(aR0a, ca + u2h2(t.x)); aR0b = hmax2(aR0b, cb + u2h2(t.y)); }
            if (m + 1 < NI) { uint2 t = *(const uint2*)(c255 + (m+1) * H + h);
                aR1a = hmax2(aR1a, ca + u2h2(t.x)); aR1b = hmax2(aR1b, cb + u2h2(t.y)); }
            if (m + 2 < NI) { uint2 t = *(const uint2*)(c255 + (m+2) * H + h);
                aR2a = hmax2(aR2a, ca + u2h2(t.x)); aR2b = hmax2(aR2b, cb + u2h2(t.y)); }
            if (m + 3 < NI) { uint2 t = *(const uint2*)(c255 + (m+3) * H + h);
                aR3a = hmax2(aR3a, ca + u2h2(t.x)); aR3b = hmax2(aR3b, cb + u2h2(t.y)); }
        }

        int js = (sub == 0) ? 1 : sub * 32;
        int je = (sub == 7) ? 254 : sub * 32 + 31;

        uint2 gu;
        gu = *(const uint2*)(gb + (size_t)(js - p0 + 256) * H); h2 gr0a = u2h2(gu.x), gr0b = u2h2(gu.y);
        gu = *(const uint2*)(gb + (size_t)(js - p0 + 255) * H); h2 gr1a = u2h2(gu.x), gr1b = u2h2(gu.y);
        gu = *(const uint2*)(gb + (size_t)(js - p0 + 254) * H); h2 gr2a = u2h2(gu.x), gr2b = u2h2(gu.y);
        gu = *(const uint2*)(gb + (size_t)(js - p0 + 253) * H); h2 gr3a = u2h2(gu.x), gr3b = u2h2(gu.y);

        int eL = (je + 1 < p0) ? (je + 1) : p0;        // [js, eL): all-left
        int mS = (js > p0) ? js : p0;                  // [mS, eM): mixed (<=4)
        int eM = (je + 1 < p0 + 4) ? (je + 1) : (p0 + 4);
        int rS = (js > p0 + 4) ? js : (p0 + 4);        // [rS, je]: all-right

#pragma unroll 4
        for (int j = js; j < eL; ++j) {
            uint2 cu = *(const uint2*)(ctb + (size_t)j * H);
            h2 ca = u2h2(cu.x), cb = u2h2(cu.y);
            aL0a = hmax2(aL0a, ca + gr0a); aL0b = hmax2(aL0b, cb + gr0b);
            aL1a = hmax2(aL1a, ca + gr1a); aL1b = hmax2(aL1b, cb + gr1b);
            aL2a = hmax2(aL2a, ca + gr2a); aL2b = hmax2(aL2b, cb + gr2b);
            aL3a = hmax2(aL3a, ca + gr3a); aL3b = hmax2(aL3b, cb + gr3b);
            gr3a = gr2a; gr3b = gr2b; gr2a = gr1a; gr2b = gr1b; gr1a = gr0a; gr1b = gr0b;
            uint2 gn = *(const uint2*)(gb + (size_t)(j + 1 - p0 + 256) * H);
            gr0a = u2h2(gn.x); gr0b = u2h2(gn.y);
        }
        for (int j = mS; j < eM; ++j) {                // <= 4 iterations
            uint2 cu = *(const uint2*)(ctb + (size_t)j * H);
            h2 ca = u2h2(cu.x), cb = u2h2(cu.y);
            h2 v0a = ca + gr0a, v0b = cb + gr0b;
            h2 v1a = ca + gr1a, v1b = cb + gr1b;
            h2 v2a = ca + gr2a, v2b = cb + gr2b;
            h2 v3a = ca + gr3a, v3b = cb + gr3b;
            if (j < p0)     { aL0a = hmax2(aL0a, v0a); aL0b = hmax2(aL0b, v0b); }
            else            { aR0a = hmax2(aR0a, v0a); aR0b = hmax2(aR0b, v0b); }
            if (j < p0 + 1) { aL1a = hmax2(aL1a, v1a); aL1b = hmax2(aL1b, v1b); }
            else            { aR1a = hmax2(aR1a, v1a); aR1b = hmax2(aR1b, v1b); }
            if (j < p0 + 2) { aL2a = hmax2(aL2a, v2a); aL2b = hmax2(aL2b, v2b); }
            else            { aR2a = hmax2(aR2a, v2a); aR2b = hmax2(aR2b, v2b); }
            if (j < p0 + 3) { aL3a = hmax2(aL3a, v3a); aL3b = hmax2(aL3b, v3b); }
            else            { aR3a = hmax2(aR3a, v3a); aR3b = hmax2(aR3b, v3b); }
            gr3a = gr2a; gr3b = gr2b; gr2a = gr1a; gr2b = gr1b; gr1a = gr0a; gr1b = gr0b;
            uint2 gn = *(const uint2*)(gb + (size_t)(j + 1 - p0 + 256) * H);
            gr0a = u2h2(gn.x); gr0b = u2h2(gn.y);
        }
#pragma unroll 4
        for (int j = rS; j <= je; ++j) {
            uint2 cu = *(const uint2*)(ctb + (size_t)j * H);
            h2 ca = u2h2(cu.x), cb = u2h2(cu.y);
            aR0a = hmax2(aR0a, ca + gr0a); aR0b = hmax2(aR0b, cb + gr0b);
            aR1a = hmax2(aR1a, ca + gr1a); aR1b = hmax2(aR1b, cb + gr1b);
            aR2a = hmax2(aR2a, ca + gr2a); aR2b = hmax2(aR2b, cb + gr2b);
            aR3a = hmax2(aR3a, ca + gr3a); aR3b = hmax2(aR3b, cb + gr3b);
            gr3a = gr2a; gr3b = gr2b; gr2a = gr1a; gr2b = gr1b; gr1a = gr0a; gr1b = gr0b;
            uint2 gn = *(const uint2*)(gb + (size_t)(j + 1 - p0 + 256) * H);
            gr0a = u2h2(gn.x); gr0b = u2h2(gn.y);
        }

        uint2* lp = lds2 + (size_t)sub * 400 + lane;
        lp[0]   = make_uint2(h2u(aL0a), h2u(aL0b)); lp[50]  = make_uint2(h2u(aR0a), h2u(aR0b));
        lp[100] = make_uint2(h2u(aL1a), h2u(aL1b)); lp[150] = make_uint2(h2u(aR1a), h2u(aR1b));
        lp[200] = make_uint2(h2u(aL2a), h2u(aL2b)); lp[250] = make_uint2(h2u(aR2a), h2u(aR2b));
        lp[300] = make_uint2(h2u(aL3a), h2u(aL3b)); lp[350] = make_uint2(h2u(aR3a), h2u(aR3b));
    }
    __syncthreads();

    if (tid < 400) {
        int k = tid / 100;
        int r = tid - k * 100;
        int hf = r / 50;
        int ln = r - hf * 50;
        int slot = (k * 2 + hf) * 50 + ln;
        uint2 v = lds2[slot];
        h2 va = u2h2(v.x), vb = u2h2(v.y);
#pragma unroll
        for (int s2 = 1; s2 < 8; s2++) {
            uint2 w = lds2[s2 * 400 + slot];
            va = hmax2(va, u2h2(w.x));
            vb = hmax2(vb, u2h2(w.y));
        }
        int m = pg * 4 + k;
        if (m < NI)
            *(uint2*)(poolf + (size_t)(b * 256 + m + 1) * 416 + hf * 200 + ln * 4)
                = make_uint2(h2u(va), h2u(vb));
    } else if (tid < 464) {                        // zero K-pad cols 400..415
        int t = tid - 400;
        int k = t >> 4, c = t & 15;
        int m = pg * 4 + k;
        if (m < NI) poolf[(size_t)(b * 256 + m + 1) * 416 + 400 + c] = 0;
    }
}

// ---------------- D: fused FC GEMM, K-split x2 + bias + end padding -> out ------
// M=2048 (b,s), N=48. 512 thr = 4 mtiles x 2 K-parts (21/21 MFMA each);
// partner combine via 4KB LDS. kp0 = pool(13) + llf kk 0..7; kp1 = llf kk 8..28.
__global__ __launch_bounds__(512) void k_fc(const unsigned short* __restrict__ poolf,
                                            const unsigned short* __restrict__ tokb,
                                            const unsigned short* __restrict__ fcWb,
                                            const float* __restrict__ fcB,
                                            float* __restrict__ out) {
    __shared__ float4 cld[4 * 64];                 // [mt][lane] 4 KB
    int n0 = blockIdx.x * 16;
    int mg = blockIdx.y;
    int tid = threadIdx.x;
    int wave = tid >> 6;
    int lane = tid & 63;
    int mt = wave & 3;
    int kp = wave >> 2;
    int quad = lane >> 4;
    int lr = lane & 15;
    int mtile = mg * 4 + mt;
    int b = mtile >> 4;
    int s0 = (mtile & 15) << 4;

    const unsigned short* pa1 = tokb + ((size_t)(b * 258 + s0 + lr) * 300 + quad * 8);
    const unsigned short* pb1 = fcWb + ((size_t)(n0 + lr) * 1344 + 416 + quad * 8);

    f32x4 acc0 = {0.f, 0.f, 0.f, 0.f};
    f32x4 acc1 = {0.f, 0.f, 0.f, 0.f};
    if (kp == 0) {
        const unsigned short* pa0 = poolf + ((size_t)(b * 256 + s0 + lr) * 416 + quad * 8);
        const unsigned short* pb0 = fcWb + ((size_t)(n0 + lr) * 1344 + quad * 8);
#pragma unroll
        for (int kk = 0; kk + 1 < 13; kk += 2) {
            half8 a0 = load_h8(pa0 + kk * 32);
            half8 b0 = load_h8(pb0 + kk * 32);
            acc0 = __builtin_amdgcn_mfma_f32_16x16x32_f16(a0, b0, acc0, 0, 0, 0);
            half8 a1 = load_h8(pa0 + kk * 32 + 32);
            half8 b1 = load_h8(pb0 + kk * 32 + 32);
            acc1 = __builtin_amdgcn_mfma_f32_16x16x32_f16(a1, b1, acc1, 0, 0, 0);
        }
        {   // part0 tail kk=12
            half8 a0 = load_h8(pa0 + 12 * 32);
            half8 b0 = load_h8(pb0 + 12 * 32);
            acc0 = __builtin_amdgcn_mfma_f32_16x16x32_f16(a0, b0, acc0, 0, 0, 0);
        }
#pragma unroll
        for (int kk = 0; kk < 8; kk += 2) {        // llf kk 0..7
            half8 a0 = load_h8(pa1 + kk * 32);
            half8 b0 = load_h8(pb1 + kk * 32);
            acc0 = __builtin_amdgcn_mfma_f32_16x16x32_f16(a0, b0, acc0, 0, 0, 0);
            half8 a1 = load_h8(pa1 + kk * 32 + 32);
            half8 b1 = load_h8(pb1 + kk * 32 + 32);
            acc1 = __builtin_amdgcn_mfma_f32_16x16x32_f16(a1, b1, acc1, 0, 0, 0);
        }
    } else {
#pragma unroll
        for (int kk = 8; kk + 1 < 29; kk += 2) {   // llf kk 8..27
            half8 a0 = load_h8(pa1 + kk * 32);
            half8 b0 = load_h8(pb1 + kk * 32);
            acc0 = __builtin_amdgcn_mfma_f32_16x16x32_f16(a0, b0, acc0, 0, 0, 0);
            half8 a1 = load_h8(pa1 + kk * 32 + 32);
            half8 b1 = load_h8(pb1 + kk * 32 + 32);
            acc1 = __builtin_amdgcn_mfma_f32_16x16x32_f16(a1, b1, acc1, 0, 0, 0);
        }
        {   // llf tail kk=28
            half8 a0 = load_h8(pa1 + 28 * 32);
            half8 b0 = load_h8(pb1 + 28 * 32);
            acc0 = __builtin_amdgcn_mfma_f32_16x16x32_f16(a0, b0, acc0, 0, 0, 0);
        }
    }
    f32x4 accw = acc0 + acc1;
    if (kp == 1) {
        cld[mt * 64 + lane] = make_float4(accw[0], accw[1], accw[2], accw[3]);
    }
    __syncthreads();
    if (kp == 0) {
        float4 p = cld[mt * 64 + lane];
        float r4[4] = {accw[0] + p.x, accw[1] + p.y, accw[2] + p.z, accw[3] + p.w};
        int l = n0 + lr;
        if (l < L) {
            float bias = fcB[l];
#pragma unroll
            for (int r = 0; r < 4; r++) {
                int s = s0 + quad * 4 + r;
                float val;
                if (s == 0 || s == S - 1) val = (l == L - 1) ? 1.0f : 0.0f;
                else                      val = r4[r] + bias;
                out[(size_t)(b * 256 + s) * L + l] = val;
            }
        }
    }
}

extern "C" void kernel_launch(void* const* d_in, const int* in_sizes, int n_in,
                              void* d_out, int out_size, void* d_ws, size_t ws_size,
                              hipStream_t stream) {
    const int*   ids      = (const int*)d_in[0];
    const float* word_emb = (const float*)d_in[1];
    const float* pf_emb   = (const float*)d_in[2];
    const float* conv_W   = (const float*)d_in[3];
    const float* conv_b   = (const float*)d_in[4];
    const float* fc_W     = (const float*)d_in[5];
    const float* fc_b     = (const float*)d_in[6];
    float* out = (float*)d_out;
    float* ws  = (float*)d_ws;

    unsigned short* tokb  = (unsigned short*)(ws + TOKB_OFF);
    unsigned short* Wr3   = (unsigned short*)(ws + WR3_OFF);
    unsigned short* fcWb  = (unsigned short*)(ws + FCWB_OFF);
    unsigned short* g     = (unsigned short*)(ws + G_OFF);
    unsigned short* c0    = (unsigned short*)(ws + C0_OFF);
    unsigned short* c255  = (unsigned short*)(ws + C255_OFF);
    unsigned short* ct    = (unsigned short*)(ws + CT_OFF);
    unsigned short* poolf = (unsigned short*)(ws + POOLF_OFF);

    k_init<<<GA_BLOCKS + PREP_BLOCKS, 256, 0, stream>>>(ids, word_emb, conv_W, fc_W,
                                                        pf_emb, tokb, Wr3, fcWb,
                                                        g, c0, c255);
    k_conv<<<dim3(13, 32), 512, 0, stream>>>(tokb, Wr3, conv_b, ct);
    k_poolA<<<dim3(64, 8), 512, 0, stream>>>(ct, g, c0, c255, poolf);
    k_fc<<<dim3(3, 32), 512, 0, stream>>>(poolf, tokb, fcWb, fc_b, out);
}